// Round 9
// baseline (240.644 us; speedup 1.0000x reference)
//
#include <hip/hip_runtime.h>
#include <hip/hip_fp16.h>

// Problem constants (from reference)
#define N_SAMPLES 524288
#define N_FEATURES 64
#define N_GATES 64
#define N_OUTPUTS 8
#define BASE_COLS 66          // N_FEATURES + 2 (zero col, one col)
#define MAX_CONN 130          // BASE + N_GATES

#define CH 8                  // gates per round
#define MAXSLOTS 512          // worst case: 64 levels x 8 padded slots
#define GWS_STR 131           // plan LDS stride for gate weights
#define STR 65                // circuit LDS row stride in half2 words (odd -> conflict-free)
// pad slot: reads const0 row (64), writes dummy row 130, weight row 64 (zeros)
#define PAD_SLOT (64 | (64 << 8) | (130 << 16) | (64 << 24))

typedef float v2f __attribute__((ext_vector_type(2)));

// ---------------------------------------------------------------------------
// top-2 insert, tie-break lower index (matches jax.lax.top_k stable order)
// ---------------------------------------------------------------------------
__device__ __forceinline__ void top2_ins(float x, int j, float& v1, int& i1, float& v2, int& i2) {
    bool gt1 = (x > v1) || (x == v1 && j < i1);
    bool gt2 = (x > v2) || (x == v2 && j < i2);
    if (gt1) { v2 = v1; i2 = i1; v1 = x; i1 = j; }
    else if (gt2) { v2 = x; i2 = j; }
}

// ---------------------------------------------------------------------------
// Kernel 1: plan (256 threads). Top-2 per gate (strip-parallel), dataflow
// levels (shfl relaxation), then ONE level-ordered slot table, each level
// padded to a multiple of 8 (rounds never span levels -> slots within a
// round are independent -> circuit batches 16 reads before 8 writes):
//   slot = row_a | row_b<<8 | row_wr<<16 | weightRow<<24
// Row space: 0-63 features, 64 const0, 65 const1, 66+g gate g, 130 dummy.
// Pads: PAD_SLOT (weight row 64 = zeros -> contributes nothing, branchless).
// Also emits wS[65][8] (= ow with a zero row appended) and nrounds.
// ---------------------------------------------------------------------------
__global__ __launch_bounds__(256) void plan_kernel(
    const float* __restrict__ gw,
    const float* __restrict__ ow,
    int*   __restrict__ tab,     // [MAXSLOTS]
    float* __restrict__ wS,      // [65][8]
    int*   __restrict__ nrp)
{
    __shared__ float gws[N_GATES * GWS_STR];            // 33,536 B
    __shared__ float pv1[4][N_GATES], pv2[4][N_GATES];  // 2 KB
    __shared__ int   pi1[4][N_GATES], pi2[4][N_GATES];  // 2 KB
    __shared__ int   tabL[MAXSLOTS];                    // 2 KB

    const int tid = threadIdx.x;

    // ---- stage 64x130 gate weights, vectorized + coalesced
    const float4* gw4 = (const float4*)gw;              // 2080 float4s
    for (int k = tid; k < (N_GATES * MAX_CONN) / 4; k += 256) {
        float4 v = gw4[k];
        int base = 4 * k;
        #pragma unroll
        for (int e = 0; e < 4; ++e) {
            int idx = base + e;
            int gi  = idx / MAX_CONN;
            int jj  = idx - gi * MAX_CONN;
            gws[gi * GWS_STR + jj] = (&v.x)[e];
        }
    }
    __syncthreads();

    // ---- partial top-2: thread (gate g, strip s), ~33 columns each
    {
        const int g = tid & 63, s = tid >> 6;
        const int avail = BASE_COLS + g;
        int j0 = s * 33;
        int j1 = j0 + 33; if (j1 > avail) j1 = avail;
        float v1 = -1e30f, v2 = -1e30f;
        int   i1 = 0x7fffffff, i2 = 0x7fffffff;
        const float* w = gws + g * GWS_STR;
        for (int j = j0; j < j1; ++j)
            top2_ins(w[j], j, v1, i1, v2, i2);
        pv1[s][g] = v1; pi1[s][g] = i1;
        pv2[s][g] = v2; pi2[s][g] = i2;
    }
    __syncthreads();

    if (tid >= 64) return;              // wave 0 finishes alone (no barriers below)
    const int l = tid;                  // lane == gate id

    // ---- merge strip partials
    float v1 = -1e30f, v2 = -1e30f;
    int   i1 = 0x7fffffff, i2 = 0x7fffffff;
    #pragma unroll
    for (int s = 0; s < 4; ++s) {
        top2_ins(pv1[s][l], pi1[s][l], v1, i1, v2, i2);
        top2_ins(pv2[s][l], pi2[s][l], v1, i1, v2, i2);
    }

    // ---- dataflow level: parallel relaxation (preds have smaller gate id)
    const bool ga = (i1 >= BASE_COLS), gb = (i2 >= BASE_COLS);
    const int  pa = ga ? (i1 - BASE_COLS) : 0;
    const int  pb = gb ? (i2 - BASE_COLS) : 0;
    int lvl = 0;
    bool changed = true;
    while (__any(changed)) {
        int la = __shfl(lvl, pa);
        int lb = __shfl(lvl, pb);
        int nl = lvl;
        if (ga && la + 1 > nl) nl = la + 1;
        if (gb && lb + 1 > nl) nl = lb + 1;
        changed = (nl != lvl);
        lvl = nl;
    }

    // ---- emission: level order, each level padded to a multiple of CH
    int base = 0, assigned = 0, myslot = 0;
    for (int L = 0; L < 64 && assigned < 64; ++L) {
        unsigned long long mask = __ballot(lvl == L);
        int c = __popcll(mask);
        if (!c) continue;
        if (lvl == L) {
            int r = __popcll(mask & ((1ull << l) - 1ull));
            myslot = base + r;
        }
        int cpad = (c + CH - 1) & ~(CH - 1);
        if (l < cpad - c) tabL[base + c + l] = PAD_SLOT;   // pads for this level
        base += cpad;
        assigned += c;
    }
    // real slot (disjoint from pad indices; same-wave DS is in-order)
    tabL[myslot] = i1 | (i2 << 8) | ((BASE_COLS + l) << 16) | (l << 24);

    // ---- copy out table, weights (+ zero row 64), round count
    for (int q = l; q < base; q += 64) tab[q] = tabL[q];
    for (int q = l; q < 65 * N_OUTPUTS; q += 64)
        wS[q] = (q < N_GATES * N_OUTPUTS) ? ow[q] : 0.0f;
    if (l == 0) *nrp = base / CH;
}

// ---------------------------------------------------------------------------
// Kernel 2: circuit. 64 threads = ONE wave per block, 128 samples (lane owns
// samples 2t, 2t+1 as one half2 word). LDS = 131 rows x stride 65 words
// = 34,060 B -> 4 blocks/CU (one wave per SIMD). ZERO barriers: columns are
// thread-private, same-wave DS is in-order.
// Per round: 8 slots from uniform s_loads -> 16 independent ds_read_b32
// (batched; round never spans a level, so reads can't alias this round's
// writes) -> one wait -> 8 hfma2 -> 8 ds_write -> 128 pk_fma inline GEMV.
// Stride 65 (odd): staging writes & row reads both <=2-way banks (free).
// ---------------------------------------------------------------------------
__global__ __launch_bounds__(64) void circuit_kernel(
    const float* __restrict__ X,
    const int*   __restrict__ tab,     // [MAXSLOTS] level-ordered slots
    const float* __restrict__ wS,      // [65][8] weights + zero row
    const int*   __restrict__ nrp,
    const float* __restrict__ scale,   // [8]
    float*       __restrict__ out)     // [N_SAMPLES][8]
{
    __shared__ __half2 buf[131 * STR];   // 34,060 B

    const int t = threadIdx.x;           // 0..63
    const long long s0 = (long long)blockIdx.x * 128;

    // ---- stage X chunk (128 samples x 64 feats) -> transposed fp16x2.
    // 1024 tasks: q = k*64+t, c4 = q&15 (float4 col), j = q>>4 (word 0..63).
    const float4* Xv = (const float4*)(X + s0 * N_FEATURES);
    #pragma unroll
    for (int k = 0; k < 16; ++k) {
        int q  = k * 64 + t;
        int c4 = q & 15;
        int j  = q >> 4;
        float4 va = Xv[(2 * j)     * 16 + c4];
        float4 vb = Xv[(2 * j + 1) * 16 + c4];
        #pragma unroll
        for (int i = 0; i < 4; ++i)
            buf[(4 * c4 + i) * STR + j] =
                __halves2half2(__float2half((&va.x)[i]), __float2half((&vb.x)[i]));
    }
    // const rows (single wave -> in-order DS, no barrier needed anywhere)
    buf[64 * STR + t] = __half2half2(__float2half(0.0f));
    buf[65 * STR + t] = __half2half2(__float2half(1.0f));

    const int nr = __builtin_amdgcn_readfirstlane(*nrp);
    const __half2 one2 = __half2half2(__float2half(1.0f));

    v2f acc[N_OUTPUTS];
    #pragma unroll
    for (int o = 0; o < N_OUTPUTS; ++o) { acc[o].x = 0.0f; acc[o].y = 0.0f; }

    for (int r = 0; r < nr; ++r) {
        // 8 slot words, uniform address -> scalar loads
        int sv[CH];
        #pragma unroll
        for (int k = 0; k < CH; ++k)
            sv[k] = __builtin_amdgcn_readfirstlane(tab[r * CH + k]);

        // ---- 16 independent reads, all issued before any use
        __half2 A[CH], B[CH];
        #pragma unroll
        for (int k = 0; k < CH; ++k) {
            int ea = sv[k] & 255;
            int eb = (sv[k] >> 8) & 255;
            A[k] = buf[ea * STR + t];
            B[k] = buf[eb * STR + t];
        }

        // ---- compute + writes (round-internal independence by construction)
        __half2 V[CH];
        #pragma unroll
        for (int k = 0; k < CH; ++k) {
            V[k] = __hfma2(__hneg2(A[k]), B[k], one2);       // 1 - a*b
            int wr = (sv[k] >> 16) & 255;
            buf[wr * STR + t] = V[k];
        }

        // ---- inline GEMV (pads hit zero weight row 64 -> branchless)
        #pragma unroll
        for (int k = 0; k < CH; ++k) {
            int gid = (sv[k] >> 24) & 255;
            const float* wp = wS + gid * N_OUTPUTS;          // uniform -> s_load
            v2f g2; g2.x = __low2float(V[k]); g2.y = __high2float(V[k]);
            #pragma unroll
            for (int o = 0; o < N_OUTPUTS; ++o) {
                v2f wv; wv.x = wp[o]; wv.y = wp[o];
                acc[o] = __builtin_elementwise_fma(g2, wv, acc[o]);  // v_pk_fma_f32
            }
        }
    }

    // ---- epilogue: scale + coalesced store (64 B/lane)
    float sc[N_OUTPUTS];
    #pragma unroll
    for (int o = 0; o < N_OUTPUTS; ++o) sc[o] = scale[o];

    float4* outv = (float4*)(out + (s0 + 2 * t) * N_OUTPUTS);
    outv[0] = make_float4(acc[0].x * sc[0], acc[1].x * sc[1], acc[2].x * sc[2], acc[3].x * sc[3]);
    outv[1] = make_float4(acc[4].x * sc[4], acc[5].x * sc[5], acc[6].x * sc[6], acc[7].x * sc[7]);
    outv[2] = make_float4(acc[0].y * sc[0], acc[1].y * sc[1], acc[2].y * sc[2], acc[3].y * sc[3]);
    outv[3] = make_float4(acc[4].y * sc[4], acc[5].y * sc[5], acc[6].y * sc[6], acc[7].y * sc[7]);
}

extern "C" void kernel_launch(void* const* d_in, const int* in_sizes, int n_in,
                              void* d_out, int out_size, void* d_ws, size_t ws_size,
                              hipStream_t stream_)
{
    const float* X     = (const float*)d_in[0];  // [524288][64]
    const float* gw    = (const float*)d_in[1];  // [64][130]
    const float* ow    = (const float*)d_in[2];  // [64][8]
    const float* scale = (const float*)d_in[3];  // [8]
    float* out = (float*)d_out;                  // [524288][8]

    char* ws = (char*)d_ws;
    int*   tab = (int*)ws;                       // 512*4 = 2048 B
    float* wS  = (float*)(ws + 2048);            // 65*8*4 = 2080 B
    int*   nrp = (int*)(ws + 2048 + 2080 + 32);  // 4 B (aligned past wS)

    plan_kernel<<<1, 256, 0, stream_>>>(gw, ow, tab, wS, nrp);

    const int blocks = N_SAMPLES / 128;          // 4096
    circuit_kernel<<<blocks, 64, 0, stream_>>>(X, tab, wS, nrp, scale, out);
}

// Round 10
// 234.713 us; speedup vs baseline: 1.0253x; 1.0253x over previous
//
#include <hip/hip_runtime.h>
#include <hip/hip_fp16.h>

// Problem constants (from reference)
#define N_SAMPLES 524288
#define N_FEATURES 64
#define N_GATES 64
#define N_OUTPUTS 8
#define BASE_COLS 66          // N_FEATURES + 2 (zero col, one col)
#define MAX_CONN 130          // BASE + N_GATES

#define NWAVES 4              // waves per circuit block
#define MAXW 192              // stream ints per wave (worst case 128 + ends)
#define ROWS 131              // 0-63 feat, 64 c0, 65 c1, 66-129 gates, 130 dummy
#define GWS_STR 131           // plan LDS stride for gate weights
#define PAD_SLOT (64 | (64 << 8) | (130 << 16))   // const0*const0 -> dummy row

typedef float v2f __attribute__((ext_vector_type(2)));

// ---------------------------------------------------------------------------
// top-2 insert, tie-break lower index (matches jax.lax.top_k stable order)
// ---------------------------------------------------------------------------
__device__ __forceinline__ void top2_ins(float x, int j, float& v1, int& i1, float& v2, int& i2) {
    bool gt1 = (x > v1) || (x == v1 && j < i1);
    bool gt2 = (x > v2) || (x == v2 && j < i2);
    if (gt1) { v2 = v1; i2 = i1; v1 = x; i1 = j; }
    else if (gt2) { v2 = x; i2 = j; }
}

// ---------------------------------------------------------------------------
// Kernel 1: plan (256 threads). Top-2 per gate (strip-parallel), dataflow
// levels (shfl relaxation), then 4 per-wave instruction streams:
//   slot int = rowA | rowB<<8 | wrRow<<16   (>= 0)
//   -1 = level barrier, -2 = end.
// Levels split round-robin over 4 waves, padded so all streams have the
// SAME barrier structure (pads compute const0*const0 -> dummy row 130).
// ---------------------------------------------------------------------------
__global__ __launch_bounds__(256) void plan_kernel(
    const float* __restrict__ gw,
    int* __restrict__ stream)             // [NWAVES][MAXW]
{
    __shared__ float gws[N_GATES * GWS_STR];            // 33,536 B
    __shared__ float pv1[4][N_GATES], pv2[4][N_GATES];  // 2 KB
    __shared__ int   pi1[4][N_GATES], pi2[4][N_GATES];  // 2 KB
    __shared__ int   streamL[NWAVES * MAXW];            // 3 KB

    const int tid = threadIdx.x;

    // ---- stage 64x130 gate weights, vectorized + coalesced
    const float4* gw4 = (const float4*)gw;              // 2080 float4s
    for (int k = tid; k < (N_GATES * MAX_CONN) / 4; k += 256) {
        float4 v = gw4[k];
        int base = 4 * k;
        #pragma unroll
        for (int e = 0; e < 4; ++e) {
            int idx = base + e;
            int gi  = idx / MAX_CONN;
            int jj  = idx - gi * MAX_CONN;
            gws[gi * GWS_STR + jj] = (&v.x)[e];
        }
    }
    __syncthreads();

    // ---- partial top-2: thread (gate g, strip s), ~33 columns each
    {
        const int g = tid & 63, s = tid >> 6;
        const int avail = BASE_COLS + g;
        int j0 = s * 33;
        int j1 = j0 + 33; if (j1 > avail) j1 = avail;
        float v1 = -1e30f, v2 = -1e30f;
        int   i1 = 0x7fffffff, i2 = 0x7fffffff;
        const float* w = gws + g * GWS_STR;
        for (int j = j0; j < j1; ++j)
            top2_ins(w[j], j, v1, i1, v2, i2);
        pv1[s][g] = v1; pi1[s][g] = i1;
        pv2[s][g] = v2; pi2[s][g] = i2;
    }
    __syncthreads();

    if (tid >= 64) return;              // wave 0 finishes alone
    const int l = tid;                  // lane == gate id

    // ---- merge strip partials
    float v1 = -1e30f, v2 = -1e30f;
    int   i1 = 0x7fffffff, i2 = 0x7fffffff;
    #pragma unroll
    for (int s = 0; s < 4; ++s) {
        top2_ins(pv1[s][l], pi1[s][l], v1, i1, v2, i2);
        top2_ins(pv2[s][l], pi2[s][l], v1, i1, v2, i2);
    }

    // ---- dataflow level: parallel relaxation (preds have smaller gate id)
    const bool ga = (i1 >= BASE_COLS), gb = (i2 >= BASE_COLS);
    const int  pa = ga ? (i1 - BASE_COLS) : 0;
    const int  pb = gb ? (i2 - BASE_COLS) : 0;
    int lvl = 0;
    bool changed = true;
    while (__any(changed)) {
        int la = __shfl(lvl, pa);
        int lb = __shfl(lvl, pb);
        int nl = lvl;
        if (ga && la + 1 > nl) nl = la + 1;
        if (gb && lb + 1 > nl) nl = lb + 1;
        changed = (nl != lvl);
        lvl = nl;
    }

    // ---- default-fill streams with END (-2); same-wave DS overwrites in-order
    for (int q = l; q < NWAVES * MAXW; q += 64) streamL[q] = -2;

    // ---- per-level: pads + barrier sentinels, record own position
    int p_base = 0, assigned = 0;
    int myW = 0, myP = 0;
    for (int L = 0; L < 64 && assigned < 64; ++L) {
        unsigned long long mask = __ballot(lvl == L);
        int c = __popcll(mask);
        if (!c) continue;
        int m = (c + NWAVES - 1) >> 2;           // steps this level
        if (lvl == L) {
            int r = __popcll(mask & ((1ull << l) - 1ull));
            myW = r & 3; myP = p_base + (r >> 2);
        }
        if (l <= m) {
            int val = (l == m) ? -1 : PAD_SLOT;
            #pragma unroll
            for (int wv = 0; wv < NWAVES; ++wv)
                streamL[wv * MAXW + p_base + l] = val;
        }
        p_base += m + 1;
        assigned += c;
    }

    // ---- scatter real slots (overwrite pads; same-wave DS is in-order)
    streamL[myW * MAXW + myP] = i1 | (i2 << 8) | ((BASE_COLS + l) << 16);

    // ---- copy out
    for (int q = l; q < NWAVES * MAXW; q += 64) stream[q] = streamL[q];
}

// ---------------------------------------------------------------------------
// Kernel 2: circuit. 256 threads = 4 waves SHARING one 131-row LDS buffer for
// the same 128 samples (33.5 KB -> 4 blocks/CU = 16 waves/CU at VGPR<=128).
// Interpreter = DATAFLOW ONLY (read,read,hfma2,write per slot) -> shortest
// possible dependent chain. GEMV deferred: after one barrier, wave w computes
// outputs {2w,2w+1} over all 64 gate rows (batched reads, no pads, replaces
// the old cross-wave reduction tree). Epilogue: 4KB LDS exchange in dead
// feature rows -> perfectly coalesced 256 x float4 store.
// Rows swizzled r*64 + (t ^ (r&31)): all accesses conflict-free.
// ---------------------------------------------------------------------------
__global__ __launch_bounds__(256, 4) void circuit_kernel(
    const float* __restrict__ X,
    const int*   __restrict__ stream,   // [NWAVES][MAXW]
    const float* __restrict__ ow,       // [N_GATES][N_OUTPUTS]
    const float* __restrict__ scale,    // [N_OUTPUTS]
    float*       __restrict__ out)      // [N_SAMPLES][N_OUTPUTS]
{
    __shared__ __half2 buf[ROWS * 64];  // 33,536 B

    const int tid = threadIdx.x;
    const int w = tid >> 6, t = tid & 63;
    const long long s0 = (long long)blockIdx.x * 128;

    // ---- preload this wave's stream into 3 VGPRs (covers MAXW=192)
    const int* st = stream + w * MAXW;
    const int sv0 = st[t], sv1 = st[64 + t], sv2 = st[128 + t];

    // ---- stage X chunk (128 samples x 64 feats) -> swizzled fp16x2 rows.
    // 1024 tasks: q = k*256+tid, c4 = q&15 (float4 col), j = q>>4 (word).
    const float4* Xv = (const float4*)(X + s0 * N_FEATURES);
    #pragma unroll
    for (int k = 0; k < 4; ++k) {
        int q  = k * 256 + tid;
        int c4 = q & 15;
        int j  = q >> 4;
        float4 va = Xv[(2 * j)     * 16 + c4];
        float4 vb = Xv[(2 * j + 1) * 16 + c4];
        int c = 4 * c4;
        buf[(c + 0) * 64 + (j ^ ((c + 0) & 31))] = __halves2half2(__float2half(va.x), __float2half(vb.x));
        buf[(c + 1) * 64 + (j ^ ((c + 1) & 31))] = __halves2half2(__float2half(va.y), __float2half(vb.y));
        buf[(c + 2) * 64 + (j ^ ((c + 2) & 31))] = __halves2half2(__float2half(va.z), __float2half(vb.z));
        buf[(c + 3) * 64 + (j ^ ((c + 3) & 31))] = __halves2half2(__float2half(va.w), __float2half(vb.w));
    }
    if (tid < 64)        buf[64 * 64 + tid]              = __half2half2(__float2half(0.0f)); // row 64 (xor 0)
    else if (tid < 128)  buf[65 * 64 + ((tid - 64) ^ 1)] = __half2half2(__float2half(1.0f)); // row 65 (xor 1)
    __syncthreads();

    const __half2 one2 = __half2half2(__float2half(1.0f));

    // ---- stream interpreter: dataflow only (no GEMV on the chain)
    int p = 0;
    while (true) {
        int sv = (p < 64)  ? __builtin_amdgcn_readlane(sv0, p)
               : (p < 128) ? __builtin_amdgcn_readlane(sv1, p - 64)
                           : __builtin_amdgcn_readlane(sv2, p - 128);
        ++p;
        if (sv < 0) {
            if (sv == -1) { __syncthreads(); continue; }   // level boundary
            break;                                          // -2: end
        }
        const int ra  =  sv        & 255;
        const int rb  = (sv >> 8)  & 255;
        const int wrr = (sv >> 16) & 255;
        __half2 a = buf[ra * 64 + (t ^ (ra & 31))];
        __half2 b = buf[rb * 64 + (t ^ (rb & 31))];
        __half2 gv = __hfma2(__hneg2(a), b, one2);          // 1 - a*b (2 samples)
        buf[wrr * 64 + (t ^ (wrr & 31))] = gv;              // pads hit dummy row 130
    }
    __syncthreads();                    // all 64 gate rows visible to all waves

    // ---- deferred GEMV: wave w owns outputs o0=2w, o1=2w+1 (no reduction tree)
    const int o0 = 2 * w, o1 = 2 * w + 1;
    v2f accP, accQ;
    accP.x = 0.0f; accP.y = 0.0f; accQ.x = 0.0f; accQ.y = 0.0f;

    #pragma unroll 8
    for (int g = 0; g < N_GATES; ++g) {
        const int row = 66 + g;
        __half2 gv = buf[row * 64 + (t ^ (row & 31))];
        v2f g2; g2.x = __low2float(gv); g2.y = __high2float(gv);
        float w0 = ow[g * N_OUTPUTS + o0];                  // uniform -> s_load
        float w1 = ow[g * N_OUTPUTS + o1];
        v2f wv0; wv0.x = w0; wv0.y = w0;
        v2f wv1; wv1.x = w1; wv1.y = w1;
        accP = __builtin_elementwise_fma(g2, wv0, accP);    // v_pk_fma_f32
        accQ = __builtin_elementwise_fma(g2, wv1, accQ);
    }
    accP.x *= scale[o0]; accP.y *= scale[o0];
    accQ.x *= scale[o1]; accQ.y *= scale[o1];

    // ---- exchange via dead feature-row LDS (rows 0-15 = 4 KB), then
    //      perfectly coalesced block store (256 x float4 = 4 KB).
    // ex layout == out layout: ex[s_local*8 + o]. Disjoint from gate rows.
    float* ex = (float*)buf;
    ex[(2 * t)     * N_OUTPUTS + o0] = accP.x;
    ex[(2 * t)     * N_OUTPUTS + o1] = accQ.x;
    ex[(2 * t + 1) * N_OUTPUTS + o0] = accP.y;
    ex[(2 * t + 1) * N_OUTPUTS + o1] = accQ.y;
    __syncthreads();

    float4* outv = (float4*)(out + s0 * N_OUTPUTS);
    outv[tid] = ((const float4*)ex)[tid];
}

extern "C" void kernel_launch(void* const* d_in, const int* in_sizes, int n_in,
                              void* d_out, int out_size, void* d_ws, size_t ws_size,
                              hipStream_t stream_)
{
    const float* X     = (const float*)d_in[0];  // [524288][64]
    const float* gw    = (const float*)d_in[1];  // [64][130]
    const float* ow    = (const float*)d_in[2];  // [64][8]
    const float* scale = (const float*)d_in[3];  // [8]
    float* out = (float*)d_out;                  // [524288][8]

    int* stream_ws = (int*)d_ws;                 // NWAVES*MAXW*4 = 3072 B

    plan_kernel<<<1, 256, 0, stream_>>>(gw, stream_ws);

    const int blocks = N_SAMPLES / 128;          // 4096
    circuit_kernel<<<blocks, 256, 0, stream_>>>(X, stream_ws, ow, scale, out);
}